// Round 2
// baseline (179.707 us; speedup 1.0000x reference)
//
#include <hip/hip_runtime.h>

#define IH 512
#define IW 512
#define OH 502
#define OW 502
#define KS 11
#define TILE 32
#define IN_T (TILE + KS - 1)   /* 42 */
#define IN_TP 44               /* padded row: 176 B, 16B-aligned, 11 chunks of 4 */
#define NCH 48                 /* 16*3 */
#define TPD 16                 /* ceil(502/32) tiles per dim */
#define C1f 0.0001f
#define C2f 0.0009f

// Gaussian(sigma=1.5, k=11) weights, precomputed in double precision.
__device__ __constant__ float g_w[KS] = {
    0.00102838f, 0.00759876f, 0.03600077f, 0.10936069f, 0.21300554f,
    0.26601173f, 0.21300554f, 0.10936069f, 0.03600077f, 0.00759876f,
    0.00102838f};

__global__ void zero_acc(double* acc) {
    if (threadIdx.x == 0) acc[0] = 0.0;
}

__global__ __launch_bounds__(256) void ssim_main(const float* __restrict__ x,
                                                 const float* __restrict__ y,
                                                 double* __restrict__ acc) {
    __shared__ float xs[IN_T][IN_TP];
    __shared__ float ys[IN_T][IN_TP];
    __shared__ float v0[TILE][IN_TP];
    __shared__ float v1[TILE][IN_TP];
    __shared__ float v2[TILE][IN_TP];
    __shared__ float v3[TILE][IN_TP];
    __shared__ float v4[TILE][IN_TP];
    __shared__ float red[4];

    const int bid = blockIdx.x;
    const int ch = bid / (TPD * TPD);
    const int tile = bid % (TPD * TPD);
    const int ti = tile / TPD, tj = tile % TPD;
    const int row0 = ti * TILE, col0 = tj * TILE;
    const float* __restrict__ xc = x + (size_t)ch * IH * IW;
    const float* __restrict__ yc = y + (size_t)ch * IH * IW;
    const int tid = threadIdx.x;

    // ---- stage 1: load 42x44 (padded) input tiles as float4 chunks ----
    // 42 rows * 11 chunks = 462 chunks
    for (int m = tid; m < IN_T * 11; m += 256) {
        const int r = m / 11, c4 = (m % 11) * 4;
        const int gr = min(row0 + r, IH - 1);
        const int gcb = col0 + c4;
        float4 xv, yv;
        if (gcb + 3 <= IW - 1) {
            xv = *(const float4*)(xc + gr * IW + gcb);
            yv = *(const float4*)(yc + gr * IW + gcb);
        } else {
            float tx[4], ty[4];
#pragma unroll
            for (int j = 0; j < 4; ++j) {
                const int gc = min(gcb + j, IW - 1);
                tx[j] = xc[gr * IW + gc];
                ty[j] = yc[gr * IW + gc];
            }
            xv = make_float4(tx[0], tx[1], tx[2], tx[3]);
            yv = make_float4(ty[0], ty[1], ty[2], ty[3]);
        }
        *(float4*)&xs[r][c4] = xv;
        *(float4*)&ys[r][c4] = yv;
    }
    __syncthreads();

    // ---- stage 2: vertical blur of 5 quantities, 4-col chunks ----
    // 32 rows * 11 chunks = 352 chunks
    for (int m = tid; m < TILE * 11; m += 256) {
        const int r = m / 11, c4 = (m % 11) * 4;
        float s0[4] = {0.f, 0.f, 0.f, 0.f};
        float s1[4] = {0.f, 0.f, 0.f, 0.f};
        float s2[4] = {0.f, 0.f, 0.f, 0.f};
        float s3[4] = {0.f, 0.f, 0.f, 0.f};
        float s4[4] = {0.f, 0.f, 0.f, 0.f};
#pragma unroll
        for (int t = 0; t < KS; ++t) {
            const float w = g_w[t];
            const float4 xv = *(const float4*)&xs[r + t][c4];
            const float4 yv = *(const float4*)&ys[r + t][c4];
            const float xa[4] = {xv.x, xv.y, xv.z, xv.w};
            const float ya[4] = {yv.x, yv.y, yv.z, yv.w};
#pragma unroll
            for (int j = 0; j < 4; ++j) {
                const float wx = w * xa[j];
                const float wy = w * ya[j];
                s0[j] += wx;
                s1[j] += wy;
                s2[j] = fmaf(wx, xa[j], s2[j]);
                s3[j] = fmaf(wy, ya[j], s3[j]);
                s4[j] = fmaf(wx, ya[j], s4[j]);
            }
        }
        *(float4*)&v0[r][c4] = make_float4(s0[0], s0[1], s0[2], s0[3]);
        *(float4*)&v1[r][c4] = make_float4(s1[0], s1[1], s1[2], s1[3]);
        *(float4*)&v2[r][c4] = make_float4(s2[0], s2[1], s2[2], s2[3]);
        *(float4*)&v3[r][c4] = make_float4(s3[0], s3[1], s3[2], s3[3]);
        *(float4*)&v4[r][c4] = make_float4(s4[0], s4[1], s4[2], s4[3]);
    }
    __syncthreads();

    // ---- stage 3: horizontal blur + ssim, one 1x4 output chunk per thread ----
    float lsum = 0.f;
    {
        const int r = tid >> 3;          // 32 rows
        const int c4 = (tid & 7) * 4;    // 8 chunks of 4 output cols
        const int gr = row0 + r;

        float m0[4], m1[4], m2[4], m3[4], m4[4];

#define HBLUR(VARR, OUT)                                                    \
        {                                                                   \
            float f[16];                                                    \
            *(float4*)&f[0]  = *(const float4*)&VARR[r][c4];                \
            *(float4*)&f[4]  = *(const float4*)&VARR[r][c4 + 4];            \
            *(float4*)&f[8]  = *(const float4*)&VARR[r][c4 + 8];            \
            *(float4*)&f[12] = *(const float4*)&VARR[r][c4 + 12];           \
            _Pragma("unroll")                                               \
            for (int cc = 0; cc < 4; ++cc) {                                \
                float s = 0.f;                                              \
                _Pragma("unroll")                                           \
                for (int t = 0; t < KS; ++t) s = fmaf(g_w[t], f[cc + t], s);\
                OUT[cc] = s;                                                \
            }                                                               \
        }

        HBLUR(v0, m0)
        HBLUR(v1, m1)
        HBLUR(v2, m2)
        HBLUR(v3, m3)
        HBLUR(v4, m4)
#undef HBLUR

        if (gr < OH) {
#pragma unroll
            for (int cc = 0; cc < 4; ++cc) {
                const int gc = col0 + c4 + cc;
                if (gc < OW) {
                    const float mux2 = m0[cc] * m0[cc];
                    const float muy2 = m1[cc] * m1[cc];
                    const float muxy = m0[cc] * m1[cc];
                    const float vx = m2[cc] - mux2;
                    const float vy = m3[cc] - muy2;
                    const float cxy = m4[cc] - muxy;
                    const float num = (2.f * muxy + C1f) * (2.f * cxy + C2f);
                    const float den = (mux2 + muy2 + C1f) * (vx + vy + C2f);
                    lsum += num / den;
                }
            }
        }
    }

    // ---- block reduce (4 waves of 64) ----
#pragma unroll
    for (int off = 32; off > 0; off >>= 1) lsum += __shfl_down(lsum, off, 64);
    const int wave = tid >> 6, lane = tid & 63;
    if (lane == 0) red[wave] = lsum;
    __syncthreads();
    if (tid == 0) {
        const float bs = red[0] + red[1] + red[2] + red[3];
        atomicAdd(acc, (double)bs);
    }
}

__global__ void finalize(const double* __restrict__ acc, float* __restrict__ out) {
    if (threadIdx.x == 0) {
        out[0] = (float)(1.0 - acc[0] / 12096192.0);  // 48*502*502
    }
}

extern "C" void kernel_launch(void* const* d_in, const int* in_sizes, int n_in,
                              void* d_out, int out_size, void* d_ws, size_t ws_size,
                              hipStream_t stream) {
    const float* x = (const float*)d_in[0];
    const float* y = (const float*)d_in[1];
    float* out = (float*)d_out;
    double* acc = (double*)d_ws;

    zero_acc<<<1, 64, 0, stream>>>(acc);
    ssim_main<<<NCH * TPD * TPD, 256, 0, stream>>>(x, y, acc);
    finalize<<<1, 64, 0, stream>>>(acc, out);
}